// Round 4
// baseline (382.973 us; speedup 1.0000x reference)
//
#include <hip/hip_runtime.h>
#include <math.h>

// MADE autoregressive sampler, incremental-by-degree, v4 (= v3 + group-index fix).
// B=8192, D=64, CTX=256, H=512. Units sorted by degree (mh = h%63+1); all
// masks triangular. Group finalizing at step i = units of degree i+1, which
// occupy [S_of(i+1), S_of(i+2)) in sorted order (v3 wrongly used S_of(i)).
// z_i is sampled at the TOP of step i, applied to a1 (incl. M1 diagonal into
// the degree-(i+1) group) before that group finalizes.
// Perf: amdgpu_waves_per_eu(4,4) pins <=128 VGPRs (v2's 64-VGPR allocation
// spilled 82 MB to scratch); uniformly padded per-step weight blocks W2g/Wog
// remove all p<c masking; addressing is running scalar pointers.

#define Bn 8192
#define Dn 64
#define CTXn 256
#define Hn 512
#define On 128
#define Rn 8   // batch rows per block

#define W2G_SZ (64 * 9 * 512)   // 294912
#define WOG_SZ (64 * 9 * 128)   //  73728
#define WCP_SZ (CTXn * Hn)      // 131072
#define W1C_SZ (Dn * Hn)        //  32768

// S_of(k) = # units with degree < k. Degrees 1..8 have 9 units, 9..63 have 8.
// Degree-k units occupy [S_of(k), S_of(k+1)). S_of(64)=512.
__device__ __forceinline__ int S_of(int k) {
  if (k <= 0) return 0;
  if (k <= 9) return 9 * (k - 1);
  return 72 + 8 * (k - 9);
}

// sorted index p -> original hidden unit h, and its degree k.
__device__ __forceinline__ int perm_of(int p, int* degout) {
  int k, t;
  if (p < 72) { k = p / 9 + 1; t = p - (k - 1) * 9; }
  else        { int pp = p - 72; k = pp / 8 + 9; t = pp - (k - 9) * 8; }
  *degout = k;
  return (k - 1) + 63 * t;
}

// ---------------- prep: padded/masked weight blocks into ws ------------------
// Step-i group = degree-(i+1) units, base S_of(i+1), size c_i (9 for i<8,
// 8 for 8<=i<=62, 0 effective at i=63 via masks).
// W2g[i][p][q]: group-i L1 unit p -> L2 unit q (M2: deg_q >= i+1), zero-padded.
// Wog[i][p][o]: group-i L2 unit p -> output o (Mo: (o&63) >= i+1), zero-padded.
// WcpT[c][q]: permuted Wc^T. W1c[i][q]: W1 col i, masked (deg_q >= i+1).
__global__ void prep_kernel(const float* __restrict__ W1, const float* __restrict__ Wc,
                            const float* __restrict__ W2, const float* __restrict__ Wo,
                            float* __restrict__ W2g, float* __restrict__ Wog,
                            float* __restrict__ WcpT, float* __restrict__ W1c) {
  int idx = blockIdx.x * 256 + threadIdx.x;
  if (idx < W2G_SZ) {
    int i = idx / 4608, rem = idx - i * 4608;
    int p = rem >> 9, q = rem & 511;
    int base = S_of(i + 1), c = S_of(i + 2) - base;   // degree-(i+1) group
    int dq; int hq = perm_of(q, &dq);
    float v = 0.f;
    if (p < c && dq >= i + 1) {            // M2: deg_out >= deg_in (= i+1)
      int dp; int hp = perm_of(base + p, &dp);
      v = W2[hq * Hn + hp];
    }
    W2g[idx] = v;
  } else if (idx < W2G_SZ + WOG_SZ) {
    int jj = idx - W2G_SZ;
    int i = jj / 1152, rem = jj - i * 1152;
    int p = rem >> 7, o = rem & 127;
    int base = S_of(i + 1), c = S_of(i + 2) - base;
    float v = 0.f;
    if (p < c && (o & 63) >= i + 1) {      // Mo: m_o = (o&63)+1 > mh = i+1
      int dp; int hp = perm_of(base + p, &dp);
      v = Wo[o * Hn + hp];
    }
    Wog[jj] = v;
  } else if (idx < W2G_SZ + WOG_SZ + WCP_SZ) {
    int jj = idx - (W2G_SZ + WOG_SZ);
    int cc = jj >> 9, q = jj & 511;
    int dq; int hq = perm_of(q, &dq);
    WcpT[jj] = Wc[hq * CTXn + cc];
  } else if (idx < W2G_SZ + WOG_SZ + WCP_SZ + W1C_SZ) {
    int jj = idx - (W2G_SZ + WOG_SZ + WCP_SZ);
    int i = jj >> 9, q = jj & 511;
    int dq; int hq = perm_of(q, &dq);
    W1c[jj] = (dq >= i + 1) ? W1[hq * Dn + i] : 0.f;   // M1 incl. diagonal
  }
}

// ---------------- main fused kernel ------------------------------------------
__global__ __launch_bounds__(256)
__attribute__((amdgpu_waves_per_eu(4, 4)))
void made_seq_kernel(
    const float* __restrict__ context, const float* __restrict__ WcpT,
    const float* __restrict__ b1,
    const float* __restrict__ W2g, const float* __restrict__ W1c,
    const float* __restrict__ Wog, const float* __restrict__ b2,
    const float* __restrict__ bo, const float* __restrict__ eps,
    float* __restrict__ out) {
  __shared__ __align__(16) float ctxR[8][264];  // [r][c], padded
  __shared__ __align__(16) float h1g[9][Rn];
  __shared__ __align__(16) float h2g[9][Rn];
  __shared__ __align__(16) float zL[Rn][Dn];
  __shared__ __align__(16) float muL[Rn][Dn];
  __shared__ __align__(16) float scL[Rn][Dn];
  __shared__ __align__(16) float epsL[Rn][Dn];
  __shared__ __align__(16) float zcur[Rn];

  int t = threadIdx.x;
  int b0 = blockIdx.x * Rn;
  int q0 = t, q1 = t + 256;                  // sorted hidden units owned
  int j  = t & 63, rg = t >> 6;              // output-col owner: cols {j, j+64}
  int rlo = 2 * rg, rhi = rlo + 1;           // for rows rlo, rhi

  int dg0, dg1; int h0 = perm_of(q0, &dg0); int h1 = perm_of(q1, &dg1);
  int g0 = dg0 - 1, g1 = dg1 - 1;            // finalize step = degree-1
  int p0 = q0 - S_of(dg0), p1 = q1 - S_of(dg1);   // offset within own group

  // ---- stage context (row-major rows in LDS) + eps ----
  #pragma unroll
  for (int r = 0; r < Rn; ++r)
    ctxR[r][t] = context[(b0 + r) * CTXn + t];            // coalesced
  for (int idx = t; idx < Rn * Dn; idx += 256)
    epsL[idx >> 6][idx & 63] = eps[(b0 + (idx >> 6)) * Dn + (idx & 63)];
  __syncthreads();

  // ---- fused ctx GEMM: a1[q] = b1[h] + ctx . WcpT[:,q] ----
  float a1_0[Rn], a1_1[Rn];
  {
    float bias0 = b1[h0], bias1 = b1[h1];
    #pragma unroll
    for (int r = 0; r < Rn; ++r) { a1_0[r] = bias0; a1_1[r] = bias1; }
  }
  {
    const float* wc = WcpT;
    for (int c4 = 0; c4 < CTXn / 4; ++c4) {
      float xr[Rn][4];
      #pragma unroll
      for (int r = 0; r < Rn; ++r) {
        float4 x = *(const float4*)&ctxR[r][4 * c4];
        xr[r][0] = x.x; xr[r][1] = x.y; xr[r][2] = x.z; xr[r][3] = x.w;
      }
      #pragma unroll
      for (int k = 0; k < 4; ++k) {
        float w0 = wc[q0];   // coalesced, L2-resident
        float w1 = wc[q1];
        #pragma unroll
        for (int r = 0; r < Rn; ++r) {
          a1_0[r] = fmaf(xr[r][k], w0, a1_0[r]);
          a1_1[r] = fmaf(xr[r][k], w1, a1_1[r]);
        }
        wc += Hn;
      }
    }
  }

  // ---- init a2 (bias) and register oacc ----
  float a2_0[Rn], a2_1[Rn];
  {
    float b20 = b2[h0], b21 = b2[h1];
    #pragma unroll
    for (int r = 0; r < Rn; ++r) { a2_0[r] = b20; a2_1[r] = b21; }
  }
  float oc00 = bo[j], oc01 = bo[j + 64];   // row rlo, cols j / j+64
  float oc10 = oc00,  oc11 = oc01;         // row rhi (same bias)

  const float* w2p = W2g;   // += 9*512 per step
  const float* wop = Wog;   // += 9*128 per step
  const float* w1p = W1c;   // += 512   per step

  // ---- sequential loop over output dims ----
  for (int i = 0; i < Dn; ++i) {
    // Phase E: output cols (i, 64+i) are final after step i-1's D update
    if (j == i) {
      float mu0 = oc00, pre0 = oc01;
      float mu1 = oc10, pre1 = oc11;
      float sc0 = fmaxf(pre0, 0.f) + __logf(1.f + __expf(-fabsf(pre0)));
      float sc1 = fmaxf(pre1, 0.f) + __logf(1.f + __expf(-fabsf(pre1)));
      float z0 = mu0 + sc0 * epsL[rlo][i];
      float z1 = mu1 + sc1 * epsL[rhi][i];
      zcur[rlo] = z0; zcur[rhi] = z1;
      zL[rlo][i] = z0; muL[rlo][i] = mu0; scL[rlo][i] = sc0;
      zL[rhi][i] = z1; muL[rhi][i] = mu1; scL[rhi][i] = sc1;
    }
    __syncthreads();   // bar 1

    // Phase F+A: a1[deg >= i+1] += z_i * W1c[i][q] (incl. degree-(i+1) group
    // = M1 diagonal), then group i (deg i+1) finalizes -> relu -> LDS
    {
      float4 za = *(const float4*)&zcur[0];
      float4 zb = *(const float4*)&zcur[4];
      float zs[8] = {za.x, za.y, za.z, za.w, zb.x, zb.y, zb.z, zb.w};
      if (g1 >= i) {
        float wv1 = w1p[q1];
        #pragma unroll
        for (int r = 0; r < Rn; ++r) a1_1[r] = fmaf(wv1, zs[r], a1_1[r]);
        if (g1 == i) {
          #pragma unroll
          for (int r = 0; r < Rn; ++r) h1g[p1][r] = fmaxf(a1_1[r], 0.f);
        }
        if (g0 >= i) {
          float wv0 = w1p[q0];
          #pragma unroll
          for (int r = 0; r < Rn; ++r) a1_0[r] = fmaf(wv0, zs[r], a1_0[r]);
          if (g0 == i) {
            #pragma unroll
            for (int r = 0; r < Rn; ++r) h1g[p0][r] = fmaxf(a1_0[r], 0.f);
          }
        }
      }
    }
    __syncthreads();   // bar 2

    // Phase B+C: a2[deg >= i+1] += W2g[i][p][q] * h1g[p][:]; group i -> h2g
    if (g1 >= i) {
      if (g0 >= i) {
        #pragma unroll
        for (int p = 0; p < 9; ++p) {
          float wv0 = w2p[p * Hn + q0];     // coalesced, no masks (padded)
          float wv1 = w2p[p * Hn + q1];
          float4 xa = *(const float4*)&h1g[p][0];
          float4 xb = *(const float4*)&h1g[p][4];
          float xs[8] = {xa.x, xa.y, xa.z, xa.w, xb.x, xb.y, xb.z, xb.w};
          #pragma unroll
          for (int r = 0; r < Rn; ++r) {
            a2_0[r] = fmaf(wv0, xs[r], a2_0[r]);
            a2_1[r] = fmaf(wv1, xs[r], a2_1[r]);
          }
        }
      } else {
        #pragma unroll
        for (int p = 0; p < 9; ++p) {
          float wv1 = w2p[p * Hn + q1];
          float4 xa = *(const float4*)&h1g[p][0];
          float4 xb = *(const float4*)&h1g[p][4];
          float xs[8] = {xa.x, xa.y, xa.z, xa.w, xb.x, xb.y, xb.z, xb.w};
          #pragma unroll
          for (int r = 0; r < Rn; ++r) a2_1[r] = fmaf(wv1, xs[r], a2_1[r]);
        }
      }
      if (g0 == i) {
        #pragma unroll
        for (int r = 0; r < Rn; ++r) h2g[p0][r] = fmaxf(a2_0[r], 0.f);
      }
      if (g1 == i) {
        #pragma unroll
        for (int r = 0; r < Rn; ++r) h2g[p1][r] = fmaxf(a2_1[r], 0.f);
      }
    }
    __syncthreads();   // bar 3

    // Phase D: register oacc += h2g . Wog[i] for cols (o&63) > i
    if (j > i) {
      #pragma unroll
      for (int p = 0; p < 9; ++p) {
        float w0 = wop[p * On + j];          // coalesced over j
        float w1 = wop[p * On + j + 64];
        float2 hv = *(const float2*)&h2g[p][rlo];   // rows adjacent, broadcast
        oc00 = fmaf(hv.x, w0, oc00); oc01 = fmaf(hv.x, w1, oc01);
        oc10 = fmaf(hv.y, w0, oc10); oc11 = fmaf(hv.y, w1, oc11);
      }
    }
    // no barrier: phase E uses this thread's own registers; LDS hazards are
    // 2+ barriers apart (zcur/h1g/h2g rewritten only after next bar 1/2).
    w2p += 9 * Hn; wop += 9 * On; w1p += Hn;
  }

  // epilogue: coalesced writes of z, mu, scale
  for (int idx = t; idx < Rn * Dn; idx += 256) {
    int r = idx >> 6, cc = idx & 63;
    out[(b0 + r) * Dn + cc] = zL[r][cc];
    out[Bn * Dn + (b0 + r) * Dn + cc] = muL[r][cc];
    out[2 * Bn * Dn + (b0 + r) * Dn + cc] = scL[r][cc];
  }
}

extern "C" void kernel_launch(void* const* d_in, const int* in_sizes, int n_in,
                              void* d_out, int out_size, void* d_ws, size_t ws_size,
                              hipStream_t stream) {
  const float* context = (const float*)d_in[0];
  const float* eps     = (const float*)d_in[1];
  const float* W1      = (const float*)d_in[2];
  const float* b1      = (const float*)d_in[3];
  const float* Wc      = (const float*)d_in[4];
  const float* W2      = (const float*)d_in[5];
  const float* b2      = (const float*)d_in[6];
  const float* Wo      = (const float*)d_in[7];
  const float* bo      = (const float*)d_in[8];
  float* out = (float*)d_out;

  float* ws   = (float*)d_ws;
  float* W2g  = ws;                 // 294912 floats
  float* Wog  = W2g + W2G_SZ;       //  73728
  float* WcpT = Wog + WOG_SZ;       // 131072
  float* W1c  = WcpT + WCP_SZ;      //  32768
  // total ws use: ~2.1 MB (L2-resident)

  int prep_elems = W2G_SZ + WOG_SZ + WCP_SZ + W1C_SZ;
  prep_kernel<<<(prep_elems + 255) / 256, 256, 0, stream>>>(
      W1, Wc, W2, Wo, W2g, Wog, WcpT, W1c);
  made_seq_kernel<<<Bn / Rn, 256, 0, stream>>>(context, WcpT, b1, W2g, W1c,
                                               Wog, b2, bo, eps, out);
}

// Round 5
// 333.519 us; speedup vs baseline: 1.1483x; 1.1483x over previous
//
#include <hip/hip_runtime.h>
#include <math.h>

// MADE autoregressive sampler, incremental-by-degree, v5.
// B=8192, D=64, CTX=256, H=512. Units sorted by degree (mh = h%63+1); all
// masks triangular. Step-i group = degree-(i+1) units, finalized at step i
// AFTER receiving z_i (M1 diagonal).
// v5 vs v4: the main 64-step loop gets `unroll(disable)` -- v4's counters
// (WRITE_SIZE 311 MB of scratch, SGPR 112, VALUBusy halved) indicate the
// compiler partially unrolled the sequential loop, multiplying the ~36-float
// accumulator live state and spilling to scratch. launch_bounds(256,2) caps
// at 256 VGPRs so single-iteration demand (~60) can never be forced to spill.

#define Bn 8192
#define Dn 64
#define CTXn 256
#define Hn 512
#define On 128
#define Rn 8   // batch rows per block

#define W2G_SZ (64 * 9 * 512)   // 294912
#define WOG_SZ (64 * 9 * 128)   //  73728
#define WCP_SZ (CTXn * Hn)      // 131072
#define W1C_SZ (Dn * Hn)        //  32768

// S_of(k) = # units with degree < k. Degrees 1..8 have 9 units, 9..63 have 8.
// Degree-k units occupy [S_of(k), S_of(k+1)). S_of(64)=512.
__device__ __forceinline__ int S_of(int k) {
  if (k <= 0) return 0;
  if (k <= 9) return 9 * (k - 1);
  return 72 + 8 * (k - 9);
}

// sorted index p -> original hidden unit h, and its degree k.
__device__ __forceinline__ int perm_of(int p, int* degout) {
  int k, t;
  if (p < 72) { k = p / 9 + 1; t = p - (k - 1) * 9; }
  else        { int pp = p - 72; k = pp / 8 + 9; t = pp - (k - 9) * 8; }
  *degout = k;
  return (k - 1) + 63 * t;
}

// ---------------- prep: padded/masked weight blocks into ws ------------------
// Step-i group = degree-(i+1) units, base S_of(i+1), size c_i (9 for i<8,
// 8 for 8<=i<=62, 0 effective at i=63 via masks).
// W2g[i][p][q]: group-i L1 unit p -> L2 unit q (M2: deg_q >= i+1), zero-padded.
// Wog[i][p][o]: group-i L2 unit p -> output o (Mo: (o&63) >= i+1), zero-padded.
// WcpT[c][q]: permuted Wc^T. W1c[i][q]: W1 col i, masked (deg_q >= i+1).
__global__ void prep_kernel(const float* __restrict__ W1, const float* __restrict__ Wc,
                            const float* __restrict__ W2, const float* __restrict__ Wo,
                            float* __restrict__ W2g, float* __restrict__ Wog,
                            float* __restrict__ WcpT, float* __restrict__ W1c) {
  int idx = blockIdx.x * 256 + threadIdx.x;
  if (idx < W2G_SZ) {
    int i = idx / 4608, rem = idx - i * 4608;
    int p = rem >> 9, q = rem & 511;
    int base = S_of(i + 1), c = S_of(i + 2) - base;   // degree-(i+1) group
    int dq; int hq = perm_of(q, &dq);
    float v = 0.f;
    if (p < c && dq >= i + 1) {            // M2: deg_out >= deg_in (= i+1)
      int dp; int hp = perm_of(base + p, &dp);
      v = W2[hq * Hn + hp];
    }
    W2g[idx] = v;
  } else if (idx < W2G_SZ + WOG_SZ) {
    int jj = idx - W2G_SZ;
    int i = jj / 1152, rem = jj - i * 1152;
    int p = rem >> 7, o = rem & 127;
    int base = S_of(i + 1), c = S_of(i + 2) - base;
    float v = 0.f;
    if (p < c && (o & 63) >= i + 1) {      // Mo: m_o = (o&63)+1 > mh = i+1
      int dp; int hp = perm_of(base + p, &dp);
      v = Wo[o * Hn + hp];
    }
    Wog[jj] = v;
  } else if (idx < W2G_SZ + WOG_SZ + WCP_SZ) {
    int jj = idx - (W2G_SZ + WOG_SZ);
    int cc = jj >> 9, q = jj & 511;
    int dq; int hq = perm_of(q, &dq);
    WcpT[jj] = Wc[hq * CTXn + cc];
  } else if (idx < W2G_SZ + WOG_SZ + WCP_SZ + W1C_SZ) {
    int jj = idx - (W2G_SZ + WOG_SZ + WCP_SZ);
    int i = jj >> 9, q = jj & 511;
    int dq; int hq = perm_of(q, &dq);
    W1c[jj] = (dq >= i + 1) ? W1[hq * Dn + i] : 0.f;   // M1 incl. diagonal
  }
}

// ---------------- main fused kernel ------------------------------------------
__global__ __launch_bounds__(256, 2)
void made_seq_kernel(
    const float* __restrict__ context, const float* __restrict__ WcpT,
    const float* __restrict__ b1,
    const float* __restrict__ W2g, const float* __restrict__ W1c,
    const float* __restrict__ Wog, const float* __restrict__ b2,
    const float* __restrict__ bo, const float* __restrict__ eps,
    float* __restrict__ out) {
  __shared__ __align__(16) float ctxR[8][264];  // [r][c], padded
  __shared__ __align__(16) float h1g[9][Rn];
  __shared__ __align__(16) float h2g[9][Rn];
  __shared__ __align__(16) float zL[Rn][Dn];
  __shared__ __align__(16) float muL[Rn][Dn];
  __shared__ __align__(16) float scL[Rn][Dn];
  __shared__ __align__(16) float epsL[Rn][Dn];
  __shared__ __align__(16) float zcur[Rn];

  int t = threadIdx.x;
  int b0 = blockIdx.x * Rn;
  int q0 = t, q1 = t + 256;                  // sorted hidden units owned
  int j  = t & 63, rg = t >> 6;              // output-col owner: cols {j, j+64}
  int rlo = 2 * rg, rhi = rlo + 1;           // for rows rlo, rhi

  int dg0, dg1; int h0 = perm_of(q0, &dg0); int h1 = perm_of(q1, &dg1);
  int g0 = dg0 - 1, g1 = dg1 - 1;            // finalize step = degree-1
  int p0 = q0 - S_of(dg0), p1 = q1 - S_of(dg1);   // offset within own group

  // ---- stage context (row-major rows in LDS) + eps ----
  #pragma unroll
  for (int r = 0; r < Rn; ++r)
    ctxR[r][t] = context[(b0 + r) * CTXn + t];            // coalesced
  for (int idx = t; idx < Rn * Dn; idx += 256)
    epsL[idx >> 6][idx & 63] = eps[(b0 + (idx >> 6)) * Dn + (idx & 63)];
  __syncthreads();

  // ---- fused ctx GEMM: a1[q] = b1[h] + ctx . WcpT[:,q] ----
  float a1_0[Rn], a1_1[Rn];
  {
    float bias0 = b1[h0], bias1 = b1[h1];
    #pragma unroll
    for (int r = 0; r < Rn; ++r) { a1_0[r] = bias0; a1_1[r] = bias1; }
  }
  {
    const float* wc = WcpT;
    #pragma clang loop unroll(disable)
    for (int c4 = 0; c4 < CTXn / 4; ++c4) {
      float xr[Rn][4];
      #pragma unroll
      for (int r = 0; r < Rn; ++r) {
        float4 x = *(const float4*)&ctxR[r][4 * c4];
        xr[r][0] = x.x; xr[r][1] = x.y; xr[r][2] = x.z; xr[r][3] = x.w;
      }
      #pragma unroll
      for (int k = 0; k < 4; ++k) {
        float w0 = wc[q0];   // coalesced, L2-resident
        float w1 = wc[q1];
        #pragma unroll
        for (int r = 0; r < Rn; ++r) {
          a1_0[r] = fmaf(xr[r][k], w0, a1_0[r]);
          a1_1[r] = fmaf(xr[r][k], w1, a1_1[r]);
        }
        wc += Hn;
      }
    }
  }

  // ---- init a2 (bias) and register oacc ----
  float a2_0[Rn], a2_1[Rn];
  {
    float b20 = b2[h0], b21 = b2[h1];
    #pragma unroll
    for (int r = 0; r < Rn; ++r) { a2_0[r] = b20; a2_1[r] = b21; }
  }
  float oc00 = bo[j], oc01 = bo[j + 64];   // row rlo, cols j / j+64
  float oc10 = oc00,  oc11 = oc01;         // row rhi (same bias)

  const float* w2p = W2g;   // += 9*512 per step
  const float* wop = Wog;   // += 9*128 per step
  const float* w1p = W1c;   // += 512   per step

  // ---- sequential loop over output dims (MUST stay rolled: unrolling
  // multiplies the ~36-float live accumulator state -> scratch spills) ----
  #pragma clang loop unroll(disable)
  for (int i = 0; i < Dn; ++i) {
    // Phase E: output cols (i, 64+i) are final after step i-1's D update
    if (j == i) {
      float mu0 = oc00, pre0 = oc01;
      float mu1 = oc10, pre1 = oc11;
      float sc0 = fmaxf(pre0, 0.f) + __logf(1.f + __expf(-fabsf(pre0)));
      float sc1 = fmaxf(pre1, 0.f) + __logf(1.f + __expf(-fabsf(pre1)));
      float z0 = mu0 + sc0 * epsL[rlo][i];
      float z1 = mu1 + sc1 * epsL[rhi][i];
      zcur[rlo] = z0; zcur[rhi] = z1;
      zL[rlo][i] = z0; muL[rlo][i] = mu0; scL[rlo][i] = sc0;
      zL[rhi][i] = z1; muL[rhi][i] = mu1; scL[rhi][i] = sc1;
    }
    __syncthreads();   // bar 1

    // Phase F+A: a1[deg >= i+1] += z_i * W1c[i][q] (incl. degree-(i+1) group
    // = M1 diagonal), then group i (deg i+1) finalizes -> relu -> LDS
    {
      float4 za = *(const float4*)&zcur[0];
      float4 zb = *(const float4*)&zcur[4];
      float zs[8] = {za.x, za.y, za.z, za.w, zb.x, zb.y, zb.z, zb.w};
      if (g1 >= i) {
        float wv1 = w1p[q1];
        #pragma unroll
        for (int r = 0; r < Rn; ++r) a1_1[r] = fmaf(wv1, zs[r], a1_1[r]);
        if (g1 == i) {
          #pragma unroll
          for (int r = 0; r < Rn; ++r) h1g[p1][r] = fmaxf(a1_1[r], 0.f);
        }
        if (g0 >= i) {
          float wv0 = w1p[q0];
          #pragma unroll
          for (int r = 0; r < Rn; ++r) a1_0[r] = fmaf(wv0, zs[r], a1_0[r]);
          if (g0 == i) {
            #pragma unroll
            for (int r = 0; r < Rn; ++r) h1g[p0][r] = fmaxf(a1_0[r], 0.f);
          }
        }
      }
    }
    __syncthreads();   // bar 2

    // Phase B+C: a2[deg >= i+1] += W2g[i][p][q] * h1g[p][:]; group i -> h2g
    if (g1 >= i) {
      if (g0 >= i) {
        #pragma unroll
        for (int p = 0; p < 9; ++p) {
          float wv0 = w2p[p * Hn + q0];     // coalesced, no masks (padded)
          float wv1 = w2p[p * Hn + q1];
          float4 xa = *(const float4*)&h1g[p][0];
          float4 xb = *(const float4*)&h1g[p][4];
          float xs[8] = {xa.x, xa.y, xa.z, xa.w, xb.x, xb.y, xb.z, xb.w};
          #pragma unroll
          for (int r = 0; r < Rn; ++r) {
            a2_0[r] = fmaf(wv0, xs[r], a2_0[r]);
            a2_1[r] = fmaf(wv1, xs[r], a2_1[r]);
          }
        }
      } else {
        #pragma unroll
        for (int p = 0; p < 9; ++p) {
          float wv1 = w2p[p * Hn + q1];
          float4 xa = *(const float4*)&h1g[p][0];
          float4 xb = *(const float4*)&h1g[p][4];
          float xs[8] = {xa.x, xa.y, xa.z, xa.w, xb.x, xb.y, xb.z, xb.w};
          #pragma unroll
          for (int r = 0; r < Rn; ++r) a2_1[r] = fmaf(wv1, xs[r], a2_1[r]);
        }
      }
      if (g0 == i) {
        #pragma unroll
        for (int r = 0; r < Rn; ++r) h2g[p0][r] = fmaxf(a2_0[r], 0.f);
      }
      if (g1 == i) {
        #pragma unroll
        for (int r = 0; r < Rn; ++r) h2g[p1][r] = fmaxf(a2_1[r], 0.f);
      }
    }
    __syncthreads();   // bar 3

    // Phase D: register oacc += h2g . Wog[i] for cols (o&63) > i
    if (j > i) {
      #pragma unroll
      for (int p = 0; p < 9; ++p) {
        float w0 = wop[p * On + j];          // coalesced over j
        float w1 = wop[p * On + j + 64];
        float2 hv = *(const float2*)&h2g[p][rlo];   // rows adjacent, broadcast
        oc00 = fmaf(hv.x, w0, oc00); oc01 = fmaf(hv.x, w1, oc01);
        oc10 = fmaf(hv.y, w0, oc10); oc11 = fmaf(hv.y, w1, oc11);
      }
    }
    // no barrier: phase E uses this thread's own registers; LDS hazards are
    // 2+ barriers apart (zcur/h1g/h2g rewritten only after next bar 1/2).
    w2p += 9 * Hn; wop += 9 * On; w1p += Hn;
  }

  // epilogue: coalesced writes of z, mu, scale
  for (int idx = t; idx < Rn * Dn; idx += 256) {
    int r = idx >> 6, cc = idx & 63;
    out[(b0 + r) * Dn + cc] = zL[r][cc];
    out[Bn * Dn + (b0 + r) * Dn + cc] = muL[r][cc];
    out[2 * Bn * Dn + (b0 + r) * Dn + cc] = scL[r][cc];
  }
}

extern "C" void kernel_launch(void* const* d_in, const int* in_sizes, int n_in,
                              void* d_out, int out_size, void* d_ws, size_t ws_size,
                              hipStream_t stream) {
  const float* context = (const float*)d_in[0];
  const float* eps     = (const float*)d_in[1];
  const float* W1      = (const float*)d_in[2];
  const float* b1      = (const float*)d_in[3];
  const float* Wc      = (const float*)d_in[4];
  const float* W2      = (const float*)d_in[5];
  const float* b2      = (const float*)d_in[6];
  const float* Wo      = (const float*)d_in[7];
  const float* bo      = (const float*)d_in[8];
  float* out = (float*)d_out;

  float* ws   = (float*)d_ws;
  float* W2g  = ws;                 // 294912 floats
  float* Wog  = W2g + W2G_SZ;       //  73728
  float* WcpT = Wog + WOG_SZ;       // 131072
  float* W1c  = WcpT + WCP_SZ;      //  32768
  // total ws use: ~2.1 MB (L2-resident)

  int prep_elems = W2G_SZ + WOG_SZ + WCP_SZ + W1C_SZ;
  prep_kernel<<<(prep_elems + 255) / 256, 256, 0, stream>>>(
      W1, Wc, W2, Wo, W2g, Wog, WcpT, W1c);
  made_seq_kernel<<<Bn / Rn, 256, 0, stream>>>(context, WcpT, b1, W2g, W1c,
                                               Wog, b2, bo, eps, out);
}

// Round 6
// 296.860 us; speedup vs baseline: 1.2901x; 1.1235x over previous
//
#include <hip/hip_runtime.h>
#include <math.h>

// MADE autoregressive sampler, incremental-by-degree, v6.
// v6 vs v5: software prefetch to hide L2 latency that the per-phase barriers
// expose (compiler drains vmcnt(0) at every s_barrier, so loads issued at
// point-of-use stall ~400cyc 3x per step). W2/W1 weights for step i+1 are
// loaded into registers during step i's D region (~600cyc before use); Wog
// goes through a double-buffered LDS block (global->reg in D(i-1), ds_write
// in FA(i), ds_read in D(i)). Everything else identical to v5.

#define Bn 8192
#define Dn 64
#define CTXn 256
#define Hn 512
#define On 128
#define Rn 8   // batch rows per block

#define W2G_SZ (64 * 9 * 512)   // 294912
#define WOG_SZ (64 * 9 * 128)   //  73728
#define WCP_SZ (CTXn * Hn)      // 131072
#define W1C_SZ (Dn * Hn)        //  32768

// S_of(k) = # units with degree < k. Degrees 1..8 have 9 units, 9..63 have 8.
// Degree-k units occupy [S_of(k), S_of(k+1)). S_of(64)=512.
__device__ __forceinline__ int S_of(int k) {
  if (k <= 0) return 0;
  if (k <= 9) return 9 * (k - 1);
  return 72 + 8 * (k - 9);
}

// sorted index p -> original hidden unit h, and its degree k.
__device__ __forceinline__ int perm_of(int p, int* degout) {
  int k, t;
  if (p < 72) { k = p / 9 + 1; t = p - (k - 1) * 9; }
  else        { int pp = p - 72; k = pp / 8 + 9; t = pp - (k - 9) * 8; }
  *degout = k;
  return (k - 1) + 63 * t;
}

// ---------------- prep: padded/masked weight blocks into ws ------------------
// Step-i group = degree-(i+1) units, base S_of(i+1), size c_i (9 for i<8,
// 8 for 8<=i<=62, 0 effective at i=63 via masks).
__global__ void prep_kernel(const float* __restrict__ W1, const float* __restrict__ Wc,
                            const float* __restrict__ W2, const float* __restrict__ Wo,
                            float* __restrict__ W2g, float* __restrict__ Wog,
                            float* __restrict__ WcpT, float* __restrict__ W1c) {
  int idx = blockIdx.x * 256 + threadIdx.x;
  if (idx < W2G_SZ) {
    int i = idx / 4608, rem = idx - i * 4608;
    int p = rem >> 9, q = rem & 511;
    int base = S_of(i + 1), c = S_of(i + 2) - base;   // degree-(i+1) group
    int dq; int hq = perm_of(q, &dq);
    float v = 0.f;
    if (p < c && dq >= i + 1) {            // M2: deg_out >= deg_in (= i+1)
      int dp; int hp = perm_of(base + p, &dp);
      v = W2[hq * Hn + hp];
    }
    W2g[idx] = v;
  } else if (idx < W2G_SZ + WOG_SZ) {
    int jj = idx - W2G_SZ;
    int i = jj / 1152, rem = jj - i * 1152;
    int p = rem >> 7, o = rem & 127;
    int base = S_of(i + 1), c = S_of(i + 2) - base;
    float v = 0.f;
    if (p < c && (o & 63) >= i + 1) {      // Mo: m_o = (o&63)+1 > mh = i+1
      int dp; int hp = perm_of(base + p, &dp);
      v = Wo[o * Hn + hp];
    }
    Wog[jj] = v;
  } else if (idx < W2G_SZ + WOG_SZ + WCP_SZ) {
    int jj = idx - (W2G_SZ + WOG_SZ);
    int cc = jj >> 9, q = jj & 511;
    int dq; int hq = perm_of(q, &dq);
    WcpT[jj] = Wc[hq * CTXn + cc];
  } else if (idx < W2G_SZ + WOG_SZ + WCP_SZ + W1C_SZ) {
    int jj = idx - (W2G_SZ + WOG_SZ + WCP_SZ);
    int i = jj >> 9, q = jj & 511;
    int dq; int hq = perm_of(q, &dq);
    W1c[jj] = (dq >= i + 1) ? W1[hq * Dn + i] : 0.f;   // M1 incl. diagonal
  }
}

// ---------------- main fused kernel ------------------------------------------
__global__ __launch_bounds__(256, 2)
void made_seq_kernel(
    const float* __restrict__ context, const float* __restrict__ WcpT,
    const float* __restrict__ b1,
    const float* __restrict__ W2g, const float* __restrict__ W1c,
    const float* __restrict__ Wog, const float* __restrict__ b2,
    const float* __restrict__ bo, const float* __restrict__ eps,
    float* __restrict__ out) {
  __shared__ __align__(16) float ctxR[8][264];  // [r][c], padded
  __shared__ __align__(16) float h1g[9][Rn];
  __shared__ __align__(16) float h2g[9][Rn];
  __shared__ __align__(16) float zL[Rn][Dn];
  __shared__ __align__(16) float muL[Rn][Dn];
  __shared__ __align__(16) float scL[Rn][Dn];
  __shared__ __align__(16) float epsL[Rn][Dn];
  __shared__ __align__(16) float zcur[Rn];
  __shared__ __align__(16) float wogL[2][1152];  // double-buffered Wog step blk

  int t = threadIdx.x;
  int b0 = blockIdx.x * Rn;
  int q0 = t, q1 = t + 256;                  // sorted hidden units owned
  int j  = t & 63, rg = t >> 6;              // output-col owner: cols {j, j+64}
  int rlo = 2 * rg, rhi = rlo + 1;           // for rows rlo, rhi

  int dg0, dg1; int h0 = perm_of(q0, &dg0); int h1 = perm_of(q1, &dg1);
  int g0 = dg0 - 1, g1 = dg1 - 1;            // finalize step = degree-1
  int p0 = q0 - S_of(dg0), p1 = q1 - S_of(dg1);   // offset within own group

  // ---- stage context (row-major rows in LDS) + eps ----
  #pragma unroll
  for (int r = 0; r < Rn; ++r)
    ctxR[r][t] = context[(b0 + r) * CTXn + t];            // coalesced
  for (int idx = t; idx < Rn * Dn; idx += 256)
    epsL[idx >> 6][idx & 63] = eps[(b0 + (idx >> 6)) * Dn + (idx & 63)];
  __syncthreads();

  // ---- fused ctx GEMM: a1[q] = b1[h] + ctx . WcpT[:,q] ----
  float a1_0[Rn], a1_1[Rn];
  {
    float bias0 = b1[h0], bias1 = b1[h1];
    #pragma unroll
    for (int r = 0; r < Rn; ++r) { a1_0[r] = bias0; a1_1[r] = bias1; }
  }
  {
    const float* wc = WcpT;
    #pragma clang loop unroll(disable)
    for (int c4 = 0; c4 < CTXn / 4; ++c4) {
      float xr[Rn][4];
      #pragma unroll
      for (int r = 0; r < Rn; ++r) {
        float4 x = *(const float4*)&ctxR[r][4 * c4];
        xr[r][0] = x.x; xr[r][1] = x.y; xr[r][2] = x.z; xr[r][3] = x.w;
      }
      #pragma unroll
      for (int k = 0; k < 4; ++k) {
        float w0 = wc[q0];   // coalesced, L2-resident
        float w1 = wc[q1];
        #pragma unroll
        for (int r = 0; r < Rn; ++r) {
          a1_0[r] = fmaf(xr[r][k], w0, a1_0[r]);
          a1_1[r] = fmaf(xr[r][k], w1, a1_1[r]);
        }
        wc += Hn;
      }
    }
  }

  // ---- init a2 (bias) and register oacc ----
  float a2_0[Rn], a2_1[Rn];
  {
    float b20 = b2[h0], b21 = b2[h1];
    #pragma unroll
    for (int r = 0; r < Rn; ++r) { a2_0[r] = b20; a2_1[r] = b21; }
  }
  float oc00 = bo[j], oc01 = bo[j + 64];   // row rlo, cols j / j+64
  float oc10 = oc00,  oc11 = oc01;         // row rhi (same bias)

  // ---- prologue prefetch: step-0 weights ----
  float w2v[18];           // current-step W2 column pair per p
  #pragma unroll
  for (int p = 0; p < 9; ++p) {
    w2v[2 * p]     = W2g[p * Hn + q0];
    w2v[2 * p + 1] = W2g[p * Hn + q1];
  }
  float w1v0 = W1c[q0], w1v1 = W1c[q1];
  float wg0, wg1, wg2, wg3, wg4;           // staged Wog (current step)
  wg0 = Wog[t]; wg1 = Wog[t + 256]; wg2 = Wog[t + 512]; wg3 = Wog[t + 768];
  wg4 = (t < 128) ? Wog[t + 1024] : 0.f;
  {  // direct fill of buffer 0 (FA(0) redundantly rewrites same values)
    wogL[0][t] = wg0; wogL[0][t + 256] = wg1; wogL[0][t + 512] = wg2;
    wogL[0][t + 768] = wg3;
    if (t < 128) wogL[0][t + 1024] = wg4;
  }

  // ---- sequential loop over output dims (MUST stay rolled: unrolling
  // multiplies live accumulator state -> scratch spills, see v4/v5) ----
  #pragma clang loop unroll(disable)
  for (int i = 0; i < Dn; ++i) {
    // Phase E: output cols (i, 64+i) are final after step i-1's D update
    if (j == i) {
      float mu0 = oc00, pre0 = oc01;
      float mu1 = oc10, pre1 = oc11;
      float sc0 = fmaxf(pre0, 0.f) + __logf(1.f + __expf(-fabsf(pre0)));
      float sc1 = fmaxf(pre1, 0.f) + __logf(1.f + __expf(-fabsf(pre1)));
      float z0 = mu0 + sc0 * epsL[rlo][i];
      float z1 = mu1 + sc1 * epsL[rhi][i];
      zcur[rlo] = z0; zcur[rhi] = z1;
      zL[rlo][i] = z0; muL[rlo][i] = mu0; scL[rlo][i] = sc0;
      zL[rhi][i] = z1; muL[rhi][i] = mu1; scL[rhi][i] = sc1;
    }
    __syncthreads();   // bar 1

    // Phase FA: commit staged Wog(i) to LDS (read in D after 2 barriers);
    // a1[deg >= i+1] += z_i * W1c[i][q] (prefetched), group i -> relu -> h1g
    {
      float* wl = wogL[i & 1];
      wl[t] = wg0; wl[t + 256] = wg1; wl[t + 512] = wg2; wl[t + 768] = wg3;
      if (t < 128) wl[t + 1024] = wg4;
    }
    {
      float4 za = *(const float4*)&zcur[0];
      float4 zb = *(const float4*)&zcur[4];
      float zs[8] = {za.x, za.y, za.z, za.w, zb.x, zb.y, zb.z, zb.w};
      if (g1 >= i) {
        #pragma unroll
        for (int r = 0; r < Rn; ++r) a1_1[r] = fmaf(w1v1, zs[r], a1_1[r]);
        if (g1 == i) {
          #pragma unroll
          for (int r = 0; r < Rn; ++r) h1g[p1][r] = fmaxf(a1_1[r], 0.f);
        }
        if (g0 >= i) {
          #pragma unroll
          for (int r = 0; r < Rn; ++r) a1_0[r] = fmaf(w1v0, zs[r], a1_0[r]);
          if (g0 == i) {
            #pragma unroll
            for (int r = 0; r < Rn; ++r) h1g[p0][r] = fmaxf(a1_0[r], 0.f);
          }
        }
      }
    }
    __syncthreads();   // bar 2

    // Phase BC: a2[deg >= i+1] += W2 (prefetched regs) * h1g; group i -> h2g
    if (g1 >= i) {
      if (g0 >= i) {
        #pragma unroll
        for (int p = 0; p < 9; ++p) {
          float wv0 = w2v[2 * p], wv1 = w2v[2 * p + 1];
          float4 xa = *(const float4*)&h1g[p][0];
          float4 xb = *(const float4*)&h1g[p][4];
          float xs[8] = {xa.x, xa.y, xa.z, xa.w, xb.x, xb.y, xb.z, xb.w};
          #pragma unroll
          for (int r = 0; r < Rn; ++r) {
            a2_0[r] = fmaf(wv0, xs[r], a2_0[r]);
            a2_1[r] = fmaf(wv1, xs[r], a2_1[r]);
          }
        }
      } else {
        #pragma unroll
        for (int p = 0; p < 9; ++p) {
          float wv1 = w2v[2 * p + 1];
          float4 xa = *(const float4*)&h1g[p][0];
          float4 xb = *(const float4*)&h1g[p][4];
          float xs[8] = {xa.x, xa.y, xa.z, xa.w, xb.x, xb.y, xb.z, xb.w};
          #pragma unroll
          for (int r = 0; r < Rn; ++r) a2_1[r] = fmaf(wv1, xs[r], a2_1[r]);
        }
      }
      if (g0 == i) {
        #pragma unroll
        for (int r = 0; r < Rn; ++r) h2g[p0][r] = fmaxf(a2_0[r], 0.f);
      }
      if (g1 == i) {
        #pragma unroll
        for (int r = 0; r < Rn; ++r) h2g[p1][r] = fmaxf(a2_1[r], 0.f);
      }
    }
    __syncthreads();   // bar 3

    // Phase D region. FIRST: issue next-step prefetches (values needed only
    // after the next bar1 drain -> full latency hidden by D+E work).
    {
      int inext = (i < 63) ? i + 1 : 63;
      const float* w2n = W2g + (size_t)inext * (9 * Hn);
      const float* w1n = W1c + inext * Hn;
      const float* won = Wog + inext * (9 * On);
      #pragma unroll
      for (int p = 0; p < 9; ++p) {
        w2v[2 * p]     = w2n[p * Hn + q0];
        w2v[2 * p + 1] = w2n[p * Hn + q1];
      }
      w1v0 = w1n[q0]; w1v1 = w1n[q1];
      wg0 = won[t]; wg1 = won[t + 256]; wg2 = won[t + 512]; wg3 = won[t + 768];
      wg4 = (t < 128) ? won[t + 1024] : 0.f;
    }
    // D work: oacc += h2g . wogL[i&1] for cols (o&63) > i  (LDS reads, ~120cyc)
    if (j > i) {
      const float* wl = wogL[i & 1];
      #pragma unroll
      for (int p = 0; p < 9; ++p) {
        float w0 = wl[p * On + j];
        float w1 = wl[p * On + j + 64];
        float2 hv = *(const float2*)&h2g[p][rlo];   // rows adjacent, broadcast
        oc00 = fmaf(hv.x, w0, oc00); oc01 = fmaf(hv.x, w1, oc01);
        oc10 = fmaf(hv.y, w0, oc10); oc11 = fmaf(hv.y, w1, oc11);
      }
    }
    // next E uses this thread's own oacc regs; LDS hazards 2+ barriers apart
  }

  // epilogue: coalesced writes of z, mu, scale
  for (int idx = t; idx < Rn * Dn; idx += 256) {
    int r = idx >> 6, cc = idx & 63;
    out[(b0 + r) * Dn + cc] = zL[r][cc];
    out[Bn * Dn + (b0 + r) * Dn + cc] = muL[r][cc];
    out[2 * Bn * Dn + (b0 + r) * Dn + cc] = scL[r][cc];
  }
}

extern "C" void kernel_launch(void* const* d_in, const int* in_sizes, int n_in,
                              void* d_out, int out_size, void* d_ws, size_t ws_size,
                              hipStream_t stream) {
  const float* context = (const float*)d_in[0];
  const float* eps     = (const float*)d_in[1];
  const float* W1      = (const float*)d_in[2];
  const float* b1      = (const float*)d_in[3];
  const float* Wc      = (const float*)d_in[4];
  const float* W2      = (const float*)d_in[5];
  const float* b2      = (const float*)d_in[6];
  const float* Wo      = (const float*)d_in[7];
  const float* bo      = (const float*)d_in[8];
  float* out = (float*)d_out;

  float* ws   = (float*)d_ws;
  float* W2g  = ws;                 // 294912 floats
  float* Wog  = W2g + W2G_SZ;       //  73728
  float* WcpT = Wog + WOG_SZ;       // 131072
  float* W1c  = WcpT + WCP_SZ;      //  32768
  // total ws use: ~2.1 MB (L2-resident)

  int prep_elems = W2G_SZ + WOG_SZ + WCP_SZ + W1C_SZ;
  prep_kernel<<<(prep_elems + 255) / 256, 256, 0, stream>>>(
      W1, Wc, W2, Wo, W2g, Wog, WcpT, W1c);
  made_seq_kernel<<<Bn / Rn, 256, 0, stream>>>(context, WcpT, b1, W2g, W1c,
                                               Wog, b2, bo, eps, out);
}